// Round 10
// baseline (425.607 us; speedup 1.0000x reference)
//
#include <hip/hip_runtime.h>

// Problem dims (fixed by setup_inputs): x [B,N,C], adapter dim D, patch grid HxH
#define B_  64
#define N_  1024
#define H_  32
#define C_  768
#define D_  8

__device__ __forceinline__ float qgelu(float v) {
    return v / (1.0f + __expf(-1.702f * v));
}

// 10-shuffle butterfly reduce over d=8: halve d at xor1/2/4, broadcast 8/16/32.
// On return acc[0] holds, in lane l, the full sum for
// dl(l) = 4*(l&1) + 2*((l>>1)&1) + ((l>>2)&1)  (all 8-lane groups identical).
__device__ __forceinline__ void reduce8(float* acc, int lane) {
    {
        const bool hi = lane & 1;
#pragma unroll
        for (int j = 0; j < 4; ++j) {
            const float a = acc[j], b = acc[j + 4];
            acc[j] = hi ? b : a;
            acc[j + 4] = hi ? a : b;
        }
#pragma unroll
        for (int j = 0; j < 4; ++j)
            acc[j] += __shfl_xor(acc[j + 4], 1, 64);
    }
    {
        const bool hi = lane & 2;
#pragma unroll
        for (int j = 0; j < 2; ++j) {
            const float a = acc[j], b = acc[j + 2];
            acc[j] = hi ? b : a;
            acc[j + 2] = hi ? a : b;
        }
#pragma unroll
        for (int j = 0; j < 2; ++j)
            acc[j] += __shfl_xor(acc[j + 2], 2, 64);
    }
    {
        const bool hi = lane & 4;
        const float a = acc[0], b = acc[1];
        acc[0] = hi ? b : a;
        acc[1] = hi ? a : b;
        acc[0] += __shfl_xor(acc[1], 4, 64);
    }
    acc[0] += __shfl_xor(acc[0], 8, 64);
    acc[0] += __shfl_xor(acc[0], 16, 64);
    acc[0] += __shfl_xor(acc[0], 32, 64);
}

// ---------------- Kernel 1: x_down = quick_gelu(x @ Wd + bd) ----------------
// v10: copy-kernel regime. Wave per row-pair (grid-stride): 6 unique
// lane-contiguous float4 loads (1 KB/instr, the proven-fast pattern),
// weights read from LDS AT USE (24 contiguous-pattern ds_read_b128/pair,
// ~12cy each) instead of 96 pinned VGPRs. ~60 VGPR + 24 KB LDS ->
// 6 blocks/CU = 24 waves/CU; DS (~22us/CU) and VALU (~24us/CU) both hide
// under the 32us VMEM floor.
__global__ __launch_bounds__(256, 6) void k_down(
    const float* __restrict__ x, const float* __restrict__ Wd,
    const float* __restrict__ bd, float* __restrict__ t1, int npairs)
{
    __shared__ float sW[D_ * C_];   // transposed: sW[d*C_ + c] = Wd[c*D_ + d]
    for (int i = threadIdx.x; i < D_ * C_; i += 256) {
        const int c = i >> 3, d = i & 7;
        sW[d * C_ + c] = Wd[i];     // Wd is [C][D] row-major
    }
    __syncthreads();

    const int wid  = threadIdx.x >> 6;
    const int lane = threadIdx.x & 63;
    const int dl   = 4 * (lane & 1) + 2 * ((lane >> 1) & 1) + ((lane >> 2) & 1);
    const float bias = bd[dl];

    const int gw = blockIdx.x * 4 + wid;
    const int nw = gridDim.x * 4;

#pragma unroll 1
    for (int p = gw; p < npairs; p += nw) {
        const float4* x0 = (const float4*)(x + (size_t)(2 * p) * C_);
        const float4* x1 = x0 + (C_ / 4);

        float4 va[3], vb[3];
#pragma unroll
        for (int k = 0; k < 3; ++k) {
            va[k] = x0[k * 64 + lane];
            vb[k] = x1[k * 64 + lane];
        }

        float a0[D_], a1[D_];
#pragma unroll
        for (int d = 0; d < D_; ++d) { a0[d] = 0.0f; a1[d] = 0.0f; }

#pragma unroll
        for (int k = 0; k < 3; ++k) {
#pragma unroll
            for (int d = 0; d < D_; ++d) {
                const float4 wv = *(const float4*)&sW[d * C_ + (k * 64 + lane) * 4];
                a0[d] += va[k].x * wv.x + va[k].y * wv.y
                       + va[k].z * wv.z + va[k].w * wv.w;
                a1[d] += vb[k].x * wv.x + vb[k].y * wv.y
                       + vb[k].z * wv.z + vb[k].w * wv.w;
            }
        }

        reduce8(a0, lane);
        reduce8(a1, lane);

        if (lane < 16) {
            const float s = (lane & 8) ? a1[0] : a0[0];
            t1[(size_t)(2 * p + ((lane >> 3) & 1)) * D_ + dl] = qgelu(s + bias);
        }
    }
}

// ------------- Kernel 2: t2 = quick_gelu(conv3x3(t1) + bc) ------------------
// (unchanged)
__global__ __launch_bounds__(256, 4) void k_conv(
    const float* __restrict__ t1, const float* __restrict__ Wc,
    const float* __restrict__ bc, float* __restrict__ t2)
{
    __shared__ float sIn[10 * H_ * D_];     // 10 rows x 32 cols x 8 ch = 10 KB
    __shared__ float sWc[9 * D_ * D_];
    __shared__ float sbc[D_];

    const int img   = blockIdx.x >> 2;
    const int strip = blockIdx.x & 3;
    const int h0    = strip * 8;
    const float* in = t1 + (size_t)img * N_ * D_;

#pragma unroll
    for (int j = 0; j < 10; ++j) {
        const int i  = threadIdx.x + j * 256;
        const int lr = i >> 8;
        const int rem = i & 255;
        const int g  = h0 - 1 + lr;
        sIn[i] = (g >= 0 && g < H_) ? in[(size_t)g * H_ * D_ + rem] : 0.0f;
    }
    for (int i = threadIdx.x; i < 9 * D_ * D_; i += 256) sWc[i] = Wc[i];
    if (threadIdx.x < D_) sbc[threadIdx.x] = bc[threadIdx.x];
    __syncthreads();

    const int lh = threadIdx.x >> 5;
    const int w  = threadIdx.x & 31;
    float acc[D_];
#pragma unroll
    for (int co = 0; co < D_; ++co) acc[co] = sbc[co];

#pragma unroll
    for (int kh = 0; kh < 3; ++kh) {
        const int lrow = lh + kh;
#pragma unroll
        for (int kw = 0; kw < 3; ++kw) {
            const int ww = w + kw - 1;
            if (ww < 0 || ww >= H_) continue;
            const float* ip = &sIn[(lrow * H_ + ww) * D_];
            const float* wp = &sWc[(kh * 3 + kw) * D_ * D_];
#pragma unroll
            for (int ci = 0; ci < D_; ++ci) {
                const float iv = ip[ci];
#pragma unroll
                for (int co = 0; co < D_; ++co)
                    acc[co] += iv * wp[ci * D_ + co];
            }
        }
    }
    float4 o0, o1;
    o0.x = qgelu(acc[0]); o0.y = qgelu(acc[1]);
    o0.z = qgelu(acc[2]); o0.w = qgelu(acc[3]);
    o1.x = qgelu(acc[4]); o1.y = qgelu(acc[5]);
    o1.z = qgelu(acc[6]); o1.w = qgelu(acc[7]);
    float* tp = t2 + ((size_t)img * N_ + (size_t)(h0 + lh) * H_ + w) * D_;
    *(float4*)tp       = o0;
    *(float4*)(tp + 4) = o1;
}

// ---------------- Kernel 3: out = t2 @ Wu + bu ------------------------------
// (unchanged: register-weight, LDS-free, write-bound)
__global__ __launch_bounds__(256, 3) void k_up(
    const float* __restrict__ t2, const float* __restrict__ Wu,
    const float* __restrict__ bu, float* __restrict__ out, int nrows)
{
    const int wid  = threadIdx.x >> 6;
    const int lane = threadIdx.x & 63;

    float4 w[3][D_];
    float4 bias[3];
#pragma unroll
    for (int j = 0; j < 3; ++j) {
        bias[j] = *(const float4*)&bu[(lane + j * 64) * 4];
#pragma unroll
        for (int d = 0; d < D_; ++d)
            w[j][d] = *(const float4*)&Wu[d * C_ + (lane + j * 64) * 4];
    }

    const int stride = gridDim.x * 4;
    for (int row = blockIdx.x * 4 + wid; row < nrows; row += stride) {
        const float4* rp = (const float4*)(t2 + (size_t)row * D_);
        const float4 ra = rp[0];
        const float4 rb = rp[1];
        const float rv[D_] = { ra.x, ra.y, ra.z, ra.w, rb.x, rb.y, rb.z, rb.w };

#pragma unroll
        for (int j = 0; j < 3; ++j) {
            float4 o = bias[j];
#pragma unroll
            for (int d = 0; d < D_; ++d) {
                o.x += rv[d] * w[j][d].x;
                o.y += rv[d] * w[j][d].y;
                o.z += rv[d] * w[j][d].z;
                o.w += rv[d] * w[j][d].w;
            }
            *(float4*)&out[(size_t)row * C_ + (size_t)(lane + j * 64) * 4] = o;
        }
    }
}

extern "C" void kernel_launch(void* const* d_in, const int* in_sizes, int n_in,
                              void* d_out, int out_size, void* d_ws, size_t ws_size,
                              hipStream_t stream) {
    const float* x  = (const float*)d_in[0];
    const float* Wd = (const float*)d_in[1];
    const float* bd = (const float*)d_in[2];
    const float* Wc = (const float*)d_in[3];
    const float* bc = (const float*)d_in[4];
    const float* Wu = (const float*)d_in[5];
    const float* bu = (const float*)d_in[6];
    float* out = (float*)d_out;

    const int nrows = B_ * N_;                  // 65536
    float* t1 = (float*)d_ws;                   // [nrows][D_]  (2 MB)
    float* t2 = t1 + (size_t)nrows * D_;        // [nrows][D_]  (2 MB)

    // K1 v10: 1536 blocks = 6/CU (LDS-limited), 24 waves/CU, grid-stride
    // over 32768 row pairs.
    k_down<<<1536, 256, 0, stream>>>(x, Wd, bd, t1, nrows / 2);
    // K2: 4 blocks per image (unchanged)
    k_conv<<<B_ * 4, 256, 0, stream>>>(t1, Wc, bc, t2);
    // K3: register-weight, LDS-free (unchanged)
    k_up<<<768, 256, 0, stream>>>(t2, Wu, bu, out, nrows);
}

// Round 11
// 110.883 us; speedup vs baseline: 3.8383x; 3.8383x over previous
//
#include <hip/hip_runtime.h>

// Problem dims (fixed by setup_inputs): x [B,N,C], adapter dim D, patch grid HxH
#define B_  64
#define N_  1024
#define H_  32
#define C_  768
#define D_  8

__device__ __forceinline__ float qgelu(float v) {
    return v / (1.0f + __expf(-1.702f * v));
}

// 10-shuffle butterfly reduce over d=8: halve d at xor1/2/4, broadcast 8/16/32.
// On return acc[0] holds, in lane l, the full sum for
// dl(l) = 4*(l&1) + 2*((l>>1)&1) + ((l>>2)&1)  (all 8-lane groups identical).
__device__ __forceinline__ void reduce8(float* acc, int lane) {
    {
        const bool hi = lane & 1;
#pragma unroll
        for (int j = 0; j < 4; ++j) {
            const float a = acc[j], b = acc[j + 4];
            acc[j] = hi ? b : a;
            acc[j + 4] = hi ? a : b;
        }
#pragma unroll
        for (int j = 0; j < 4; ++j)
            acc[j] += __shfl_xor(acc[j + 4], 1, 64);
    }
    {
        const bool hi = lane & 2;
#pragma unroll
        for (int j = 0; j < 2; ++j) {
            const float a = acc[j], b = acc[j + 2];
            acc[j] = hi ? b : a;
            acc[j + 2] = hi ? a : b;
        }
#pragma unroll
        for (int j = 0; j < 2; ++j)
            acc[j] += __shfl_xor(acc[j + 2], 2, 64);
    }
    {
        const bool hi = lane & 4;
        const float a = acc[0], b = acc[1];
        acc[0] = hi ? b : a;
        acc[1] = hi ? a : b;
        acc[0] += __shfl_xor(acc[1], 4, 64);
    }
    acc[0] += __shfl_xor(acc[0], 8, 64);
    acc[0] += __shfl_xor(acc[0], 16, 64);
    acc[0] += __shfl_xor(acc[0], 32, 64);
}

// ---------------- Kernel 1: x_down = quick_gelu(x @ Wd + bd) ----------------
// v11 = v10's structure with the launch_bounds spill-trap removed.
// Wave per row-pair, 4 contiguous pairs per wave (exact cover, no stride
// loop). 6 unique lane-contiguous float4 loads per pair (1 KB/instr),
// weights from LDS at use (24 contiguous ds_read_b128/pair). Natural VGPR
// (~56-64, no min-waves bound -> no occupancy-step spills); 24 KB LDS ->
// 6 blocks/CU = 24 waves/CU. TLP hides both VMEM and DS latency.
__global__ __launch_bounds__(256) void k_down(
    const float* __restrict__ x, const float* __restrict__ Wd,
    const float* __restrict__ bd, float* __restrict__ t1)
{
    __shared__ float sW[D_ * C_];   // transposed: sW[d*C_ + c] = Wd[c*D_ + d]
    for (int i = threadIdx.x; i < D_ * C_; i += 256) {
        const int c = i >> 3, d = i & 7;
        sW[d * C_ + c] = Wd[i];     // Wd is [C][D] row-major
    }
    __syncthreads();

    const int wid  = threadIdx.x >> 6;
    const int lane = threadIdx.x & 63;
    const int dl   = 4 * (lane & 1) + 2 * ((lane >> 1) & 1) + ((lane >> 2) & 1);
    const float bias = bd[dl];

    const int gw = blockIdx.x * 4 + wid;   // 8192 waves x 4 pairs = 32768 pairs

#pragma unroll 1
    for (int i = 0; i < 4; ++i) {
        const int p = gw * 4 + i;          // contiguous 8 rows per wave
        const float4* x0 = (const float4*)(x + (size_t)(2 * p) * C_);
        const float4* x1 = x0 + (C_ / 4);

        float4 va[3], vb[3];
#pragma unroll
        for (int k = 0; k < 3; ++k) {
            va[k] = x0[k * 64 + lane];
            vb[k] = x1[k * 64 + lane];
        }

        float a0[D_], a1[D_];
#pragma unroll
        for (int d = 0; d < D_; ++d) { a0[d] = 0.0f; a1[d] = 0.0f; }

#pragma unroll
        for (int k = 0; k < 3; ++k) {
#pragma unroll
            for (int d = 0; d < D_; ++d) {
                const float4 wv = *(const float4*)&sW[d * C_ + (k * 64 + lane) * 4];
                a0[d] += va[k].x * wv.x + va[k].y * wv.y
                       + va[k].z * wv.z + va[k].w * wv.w;
                a1[d] += vb[k].x * wv.x + vb[k].y * wv.y
                       + vb[k].z * wv.z + vb[k].w * wv.w;
            }
        }

        reduce8(a0, lane);
        reduce8(a1, lane);

        if (lane < 16) {
            const float s = (lane & 8) ? a1[0] : a0[0];
            t1[(size_t)(2 * p + ((lane >> 3) & 1)) * D_ + dl] = qgelu(s + bias);
        }
    }
}

// ------------- Kernel 2: t2 = quick_gelu(conv3x3(t1) + bc) ------------------
// (unchanged)
__global__ __launch_bounds__(256, 4) void k_conv(
    const float* __restrict__ t1, const float* __restrict__ Wc,
    const float* __restrict__ bc, float* __restrict__ t2)
{
    __shared__ float sIn[10 * H_ * D_];     // 10 rows x 32 cols x 8 ch = 10 KB
    __shared__ float sWc[9 * D_ * D_];
    __shared__ float sbc[D_];

    const int img   = blockIdx.x >> 2;
    const int strip = blockIdx.x & 3;
    const int h0    = strip * 8;
    const float* in = t1 + (size_t)img * N_ * D_;

#pragma unroll
    for (int j = 0; j < 10; ++j) {
        const int i  = threadIdx.x + j * 256;
        const int lr = i >> 8;
        const int rem = i & 255;
        const int g  = h0 - 1 + lr;
        sIn[i] = (g >= 0 && g < H_) ? in[(size_t)g * H_ * D_ + rem] : 0.0f;
    }
    for (int i = threadIdx.x; i < 9 * D_ * D_; i += 256) sWc[i] = Wc[i];
    if (threadIdx.x < D_) sbc[threadIdx.x] = bc[threadIdx.x];
    __syncthreads();

    const int lh = threadIdx.x >> 5;
    const int w  = threadIdx.x & 31;
    float acc[D_];
#pragma unroll
    for (int co = 0; co < D_; ++co) acc[co] = sbc[co];

#pragma unroll
    for (int kh = 0; kh < 3; ++kh) {
        const int lrow = lh + kh;
#pragma unroll
        for (int kw = 0; kw < 3; ++kw) {
            const int ww = w + kw - 1;
            if (ww < 0 || ww >= H_) continue;
            const float* ip = &sIn[(lrow * H_ + ww) * D_];
            const float* wp = &sWc[(kh * 3 + kw) * D_ * D_];
#pragma unroll
            for (int ci = 0; ci < D_; ++ci) {
                const float iv = ip[ci];
#pragma unroll
                for (int co = 0; co < D_; ++co)
                    acc[co] += iv * wp[ci * D_ + co];
            }
        }
    }
    float4 o0, o1;
    o0.x = qgelu(acc[0]); o0.y = qgelu(acc[1]);
    o0.z = qgelu(acc[2]); o0.w = qgelu(acc[3]);
    o1.x = qgelu(acc[4]); o1.y = qgelu(acc[5]);
    o1.z = qgelu(acc[6]); o1.w = qgelu(acc[7]);
    float* tp = t2 + ((size_t)img * N_ + (size_t)(h0 + lh) * H_ + w) * D_;
    *(float4*)tp       = o0;
    *(float4*)(tp + 4) = o1;
}

// ---------------- Kernel 3: out = t2 @ Wu + bu ------------------------------
// (unchanged: register-weight, LDS-free, write-bound)
__global__ __launch_bounds__(256, 3) void k_up(
    const float* __restrict__ t2, const float* __restrict__ Wu,
    const float* __restrict__ bu, float* __restrict__ out, int nrows)
{
    const int wid  = threadIdx.x >> 6;
    const int lane = threadIdx.x & 63;

    float4 w[3][D_];
    float4 bias[3];
#pragma unroll
    for (int j = 0; j < 3; ++j) {
        bias[j] = *(const float4*)&bu[(lane + j * 64) * 4];
#pragma unroll
        for (int d = 0; d < D_; ++d)
            w[j][d] = *(const float4*)&Wu[d * C_ + (lane + j * 64) * 4];
    }

    const int stride = gridDim.x * 4;
    for (int row = blockIdx.x * 4 + wid; row < nrows; row += stride) {
        const float4* rp = (const float4*)(t2 + (size_t)row * D_);
        const float4 ra = rp[0];
        const float4 rb = rp[1];
        const float rv[D_] = { ra.x, ra.y, ra.z, ra.w, rb.x, rb.y, rb.z, rb.w };

#pragma unroll
        for (int j = 0; j < 3; ++j) {
            float4 o = bias[j];
#pragma unroll
            for (int d = 0; d < D_; ++d) {
                o.x += rv[d] * w[j][d].x;
                o.y += rv[d] * w[j][d].y;
                o.z += rv[d] * w[j][d].z;
                o.w += rv[d] * w[j][d].w;
            }
            *(float4*)&out[(size_t)row * C_ + (size_t)(lane + j * 64) * 4] = o;
        }
    }
}

extern "C" void kernel_launch(void* const* d_in, const int* in_sizes, int n_in,
                              void* d_out, int out_size, void* d_ws, size_t ws_size,
                              hipStream_t stream) {
    const float* x  = (const float*)d_in[0];
    const float* Wd = (const float*)d_in[1];
    const float* bd = (const float*)d_in[2];
    const float* Wc = (const float*)d_in[3];
    const float* bc = (const float*)d_in[4];
    const float* Wu = (const float*)d_in[5];
    const float* bu = (const float*)d_in[6];
    float* out = (float*)d_out;

    const int nrows = B_ * N_;                  // 65536
    float* t1 = (float*)d_ws;                   // [nrows][D_]  (2 MB)
    float* t2 = t1 + (size_t)nrows * D_;        // [nrows][D_]  (2 MB)

    // K1 v11: 2048 blocks x 4 waves x 4 pairs = 32768 pairs exactly.
    // Natural VGPR (no min-waves bound), 6 blocks/CU by LDS = 24 waves/CU.
    k_down<<<2048, 256, 0, stream>>>(x, Wd, bd, t1);
    // K2: 4 blocks per image (unchanged)
    k_conv<<<B_ * 4, 256, 0, stream>>>(t1, Wc, bc, t2);
    // K3: register-weight, LDS-free (unchanged)
    k_up<<<768, 256, 0, stream>>>(t2, Wu, bu, out, nrows);
}

// Round 12
// 101.835 us; speedup vs baseline: 4.1794x; 1.0889x over previous
//
#include <hip/hip_runtime.h>

// Problem dims (fixed by setup_inputs): x [B,N,C], adapter dim D, patch grid HxH
#define B_  64
#define N_  1024
#define H_  32
#define C_  768
#define D_  8

__device__ __forceinline__ float qgelu(float v) {
    return v / (1.0f + __expf(-1.702f * v));
}

// non-temporal float4 load/store (emit global_load/store_dwordx4 with nt —
// no L1/L2 allocation for streaming data)
typedef float f32x4_t __attribute__((ext_vector_type(4)));
__device__ __forceinline__ float4 ntload4(const float4* p) {
    f32x4_t v = __builtin_nontemporal_load((const f32x4_t*)p);
    return make_float4(v.x, v.y, v.z, v.w);
}
__device__ __forceinline__ void ntstore4(float4 v, float4* p) {
    f32x4_t t; t.x = v.x; t.y = v.y; t.z = v.z; t.w = v.w;
    __builtin_nontemporal_store(t, (f32x4_t*)p);
}

// 10-shuffle butterfly reduce over d=8: halve d at xor1/2/4, broadcast 8/16/32.
// On return acc[0] holds, in lane l, the full sum for
// dl(l) = 4*(l&1) + 2*((l>>1)&1) + ((l>>2)&1)  (all 8-lane groups identical).
__device__ __forceinline__ void reduce8(float* acc, int lane) {
    {
        const bool hi = lane & 1;
#pragma unroll
        for (int j = 0; j < 4; ++j) {
            const float a = acc[j], b = acc[j + 4];
            acc[j] = hi ? b : a;
            acc[j + 4] = hi ? a : b;
        }
#pragma unroll
        for (int j = 0; j < 4; ++j)
            acc[j] += __shfl_xor(acc[j + 4], 1, 64);
    }
    {
        const bool hi = lane & 2;
#pragma unroll
        for (int j = 0; j < 2; ++j) {
            const float a = acc[j], b = acc[j + 2];
            acc[j] = hi ? b : a;
            acc[j + 2] = hi ? a : b;
        }
#pragma unroll
        for (int j = 0; j < 2; ++j)
            acc[j] += __shfl_xor(acc[j + 2], 2, 64);
    }
    {
        const bool hi = lane & 4;
        const float a = acc[0], b = acc[1];
        acc[0] = hi ? b : a;
        acc[1] = hi ? a : b;
        acc[0] += __shfl_xor(acc[1], 4, 64);
    }
    acc[0] += __shfl_xor(acc[0], 8, 64);
    acc[0] += __shfl_xor(acc[0], 16, 64);
    acc[0] += __shfl_xor(acc[0], 32, 64);
}

// ---------------- Kernel 1: x_down = quick_gelu(x @ Wd + bd) ----------------
// v12 = v11 with NON-TEMPORAL x loads (streaming: no L1 allocation).
// Wave per row-pair, 4 contiguous pairs per wave. 6 unique lane-contiguous
// float4 loads per pair (1 KB/instr); weights from LDS at use. Natural VGPR,
// 24 KB LDS -> 6 blocks/CU = 24 waves/CU.
__global__ __launch_bounds__(256) void k_down(
    const float* __restrict__ x, const float* __restrict__ Wd,
    const float* __restrict__ bd, float* __restrict__ t1)
{
    __shared__ float sW[D_ * C_];   // transposed: sW[d*C_ + c] = Wd[c*D_ + d]
    for (int i = threadIdx.x; i < D_ * C_; i += 256) {
        const int c = i >> 3, d = i & 7;
        sW[d * C_ + c] = Wd[i];     // Wd is [C][D] row-major
    }
    __syncthreads();

    const int wid  = threadIdx.x >> 6;
    const int lane = threadIdx.x & 63;
    const int dl   = 4 * (lane & 1) + 2 * ((lane >> 1) & 1) + ((lane >> 2) & 1);
    const float bias = bd[dl];

    const int gw = blockIdx.x * 4 + wid;   // 8192 waves x 4 pairs = 32768 pairs

#pragma unroll 1
    for (int i = 0; i < 4; ++i) {
        const int p = gw * 4 + i;          // contiguous 8 rows per wave
        const float4* x0 = (const float4*)(x + (size_t)(2 * p) * C_);
        const float4* x1 = x0 + (C_ / 4);

        float4 va[3], vb[3];
#pragma unroll
        for (int k = 0; k < 3; ++k) {
            va[k] = ntload4(&x0[k * 64 + lane]);
            vb[k] = ntload4(&x1[k * 64 + lane]);
        }

        float a0[D_], a1[D_];
#pragma unroll
        for (int d = 0; d < D_; ++d) { a0[d] = 0.0f; a1[d] = 0.0f; }

#pragma unroll
        for (int k = 0; k < 3; ++k) {
#pragma unroll
            for (int d = 0; d < D_; ++d) {
                const float4 wv = *(const float4*)&sW[d * C_ + (k * 64 + lane) * 4];
                a0[d] += va[k].x * wv.x + va[k].y * wv.y
                       + va[k].z * wv.z + va[k].w * wv.w;
                a1[d] += vb[k].x * wv.x + vb[k].y * wv.y
                       + vb[k].z * wv.z + vb[k].w * wv.w;
            }
        }

        reduce8(a0, lane);
        reduce8(a1, lane);

        if (lane < 16) {
            const float s = (lane & 8) ? a1[0] : a0[0];
            t1[(size_t)(2 * p + ((lane >> 3) & 1)) * D_ + dl] = qgelu(s + bias);
        }
    }
}

// ------------- Kernel 2: t2 = quick_gelu(conv3x3(t1) + bc) ------------------
// (unchanged)
__global__ __launch_bounds__(256, 4) void k_conv(
    const float* __restrict__ t1, const float* __restrict__ Wc,
    const float* __restrict__ bc, float* __restrict__ t2)
{
    __shared__ float sIn[10 * H_ * D_];     // 10 rows x 32 cols x 8 ch = 10 KB
    __shared__ float sWc[9 * D_ * D_];
    __shared__ float sbc[D_];

    const int img   = blockIdx.x >> 2;
    const int strip = blockIdx.x & 3;
    const int h0    = strip * 8;
    const float* in = t1 + (size_t)img * N_ * D_;

#pragma unroll
    for (int j = 0; j < 10; ++j) {
        const int i  = threadIdx.x + j * 256;
        const int lr = i >> 8;
        const int rem = i & 255;
        const int g  = h0 - 1 + lr;
        sIn[i] = (g >= 0 && g < H_) ? in[(size_t)g * H_ * D_ + rem] : 0.0f;
    }
    for (int i = threadIdx.x; i < 9 * D_ * D_; i += 256) sWc[i] = Wc[i];
    if (threadIdx.x < D_) sbc[threadIdx.x] = bc[threadIdx.x];
    __syncthreads();

    const int lh = threadIdx.x >> 5;
    const int w  = threadIdx.x & 31;
    float acc[D_];
#pragma unroll
    for (int co = 0; co < D_; ++co) acc[co] = sbc[co];

#pragma unroll
    for (int kh = 0; kh < 3; ++kh) {
        const int lrow = lh + kh;
#pragma unroll
        for (int kw = 0; kw < 3; ++kw) {
            const int ww = w + kw - 1;
            if (ww < 0 || ww >= H_) continue;
            const float* ip = &sIn[(lrow * H_ + ww) * D_];
            const float* wp = &sWc[(kh * 3 + kw) * D_ * D_];
#pragma unroll
            for (int ci = 0; ci < D_; ++ci) {
                const float iv = ip[ci];
#pragma unroll
                for (int co = 0; co < D_; ++co)
                    acc[co] += iv * wp[ci * D_ + co];
            }
        }
    }
    float4 o0, o1;
    o0.x = qgelu(acc[0]); o0.y = qgelu(acc[1]);
    o0.z = qgelu(acc[2]); o0.w = qgelu(acc[3]);
    o1.x = qgelu(acc[4]); o1.y = qgelu(acc[5]);
    o1.z = qgelu(acc[6]); o1.w = qgelu(acc[7]);
    float* tp = t2 + ((size_t)img * N_ + (size_t)(h0 + lh) * H_ + w) * D_;
    *(float4*)tp       = o0;
    *(float4*)(tp + 4) = o1;
}

// ---------------- Kernel 3: out = t2 @ Wu + bu ------------------------------
// v12: NON-TEMPORAL out stores — out (201 MB, never read) must not evict x
// from the 256 MB Infinity Cache between graph replays; x L3-residency is
// what lets k_down's reads recycle miss-slots at L3 latency.
__global__ __launch_bounds__(256, 3) void k_up(
    const float* __restrict__ t2, const float* __restrict__ Wu,
    const float* __restrict__ bu, float* __restrict__ out, int nrows)
{
    const int wid  = threadIdx.x >> 6;
    const int lane = threadIdx.x & 63;

    float4 w[3][D_];
    float4 bias[3];
#pragma unroll
    for (int j = 0; j < 3; ++j) {
        bias[j] = *(const float4*)&bu[(lane + j * 64) * 4];
#pragma unroll
        for (int d = 0; d < D_; ++d)
            w[j][d] = *(const float4*)&Wu[d * C_ + (lane + j * 64) * 4];
    }

    const int stride = gridDim.x * 4;
    for (int row = blockIdx.x * 4 + wid; row < nrows; row += stride) {
        const float4* rp = (const float4*)(t2 + (size_t)row * D_);
        const float4 ra = rp[0];
        const float4 rb = rp[1];
        const float rv[D_] = { ra.x, ra.y, ra.z, ra.w, rb.x, rb.y, rb.z, rb.w };

#pragma unroll
        for (int j = 0; j < 3; ++j) {
            float4 o = bias[j];
#pragma unroll
            for (int d = 0; d < D_; ++d) {
                o.x += rv[d] * w[j][d].x;
                o.y += rv[d] * w[j][d].y;
                o.z += rv[d] * w[j][d].z;
                o.w += rv[d] * w[j][d].w;
            }
            ntstore4(o, (float4*)&out[(size_t)row * C_ + (size_t)(lane + j * 64) * 4]);
        }
    }
}

extern "C" void kernel_launch(void* const* d_in, const int* in_sizes, int n_in,
                              void* d_out, int out_size, void* d_ws, size_t ws_size,
                              hipStream_t stream) {
    const float* x  = (const float*)d_in[0];
    const float* Wd = (const float*)d_in[1];
    const float* bd = (const float*)d_in[2];
    const float* Wc = (const float*)d_in[3];
    const float* bc = (const float*)d_in[4];
    const float* Wu = (const float*)d_in[5];
    const float* bu = (const float*)d_in[6];
    float* out = (float*)d_out;

    const int nrows = B_ * N_;                  // 65536
    float* t1 = (float*)d_ws;                   // [nrows][D_]  (2 MB)
    float* t2 = t1 + (size_t)nrows * D_;        // [nrows][D_]  (2 MB)

    // K1 v12: 2048 blocks x 4 waves x 4 pairs = 32768 pairs exactly; nt loads.
    k_down<<<2048, 256, 0, stream>>>(x, Wd, bd, t1);
    // K2: 4 blocks per image (unchanged)
    k_conv<<<B_ * 4, 256, 0, stream>>>(t1, Wc, bc, t2);
    // K3: register-weight, LDS-free, nt out stores.
    k_up<<<768, 256, 0, stream>>>(t2, Wu, bu, out, nrows);
}